// Round 3
// baseline (473.059 us; speedup 1.0000x reference)
//
#include <hip/hip_runtime.h>

// ReluField: out[n,c] = relu( sum_{8 corners} field[clip(fl+off)][c] * prod_d |off_d - frac_d| )
// Grid 256x256x256x4 fp32, N = 2,000,000 points.
// Weight note: |corner - x| = |off - frac|  ->  off==0 weight = frac, off==1 weight = 1-frac
// (this is the reference's "swapped" trilinear weighting — be faithful to it).

#define SPATIAL 256
#define CHANNELS 4

__global__ __launch_bounds__(256) void relu_field_kernel(
    const float* __restrict__ coords,   // [N,3]
    const float* __restrict__ field,    // [256,256,256,4]
    float* __restrict__ out,            // [N,4]
    int n)
{
    int i = blockIdx.x * blockDim.x + threadIdx.x;
    if (i >= n) return;

    const float cx = coords[3 * i + 0] * (float)SPATIAL;
    const float cy = coords[3 * i + 1] * (float)SPATIAL;
    const float cz = coords[3 * i + 2] * (float)SPATIAL;

    const float flx = floorf(cx), fly = floorf(cy), flz = floorf(cz);
    const float fx = cx - flx, fy = cy - fly, fz = cz - flz;

    int ix0 = (int)flx, iy0 = (int)fly, iz0 = (int)flz;
    // clip like the reference (jnp.clip(idx, 0, 255))
    ix0 = min(max(ix0, 0), SPATIAL - 1);
    iy0 = min(max(iy0, 0), SPATIAL - 1);
    iz0 = min(max(iz0, 0), SPATIAL - 1);
    const int ix1 = min(ix0 + 1, SPATIAL - 1);
    const int iy1 = min(iy0 + 1, SPATIAL - 1);
    const int iz1 = min(iz0 + 1, SPATIAL - 1);

    // reference weight: off==0 -> frac, off==1 -> 1-frac
    const float wx0 = fx, wx1 = 1.0f - fx;
    const float wy0 = fy, wy1 = 1.0f - fy;
    const float wz0 = fz, wz1 = 1.0f - fz;

    // row base offsets (in float4 units): ((ix*256 + iy)*256 + iz)
    const long b00 = ((long)ix0 * SPATIAL + iy0) * SPATIAL;
    const long b01 = ((long)ix0 * SPATIAL + iy1) * SPATIAL;
    const long b10 = ((long)ix1 * SPATIAL + iy0) * SPATIAL;
    const long b11 = ((long)ix1 * SPATIAL + iy1) * SPATIAL;

    const float4* __restrict__ f4 = reinterpret_cast<const float4*>(field);

    // Issue all 8 loads up front for ILP (independent global_load_dwordx4).
    const float4 v000 = f4[b00 + iz0];
    const float4 v001 = f4[b00 + iz1];
    const float4 v010 = f4[b01 + iz0];
    const float4 v011 = f4[b01 + iz1];
    const float4 v100 = f4[b10 + iz0];
    const float4 v101 = f4[b10 + iz1];
    const float4 v110 = f4[b11 + iz0];
    const float4 v111 = f4[b11 + iz1];

    const float w000 = wx0 * wy0 * wz0;
    const float w001 = wx0 * wy0 * wz1;
    const float w010 = wx0 * wy1 * wz0;
    const float w011 = wx0 * wy1 * wz1;
    const float w100 = wx1 * wy0 * wz0;
    const float w101 = wx1 * wy0 * wz1;
    const float w110 = wx1 * wy1 * wz0;
    const float w111 = wx1 * wy1 * wz1;

    float4 acc;
    acc.x = v000.x * w000; acc.y = v000.y * w000; acc.z = v000.z * w000; acc.w = v000.w * w000;
    acc.x += v001.x * w001; acc.y += v001.y * w001; acc.z += v001.z * w001; acc.w += v001.w * w001;
    acc.x += v010.x * w010; acc.y += v010.y * w010; acc.z += v010.z * w010; acc.w += v010.w * w010;
    acc.x += v011.x * w011; acc.y += v011.y * w011; acc.z += v011.z * w011; acc.w += v011.w * w011;
    acc.x += v100.x * w100; acc.y += v100.y * w100; acc.z += v100.z * w100; acc.w += v100.w * w100;
    acc.x += v101.x * w101; acc.y += v101.y * w101; acc.z += v101.z * w101; acc.w += v101.w * w101;
    acc.x += v110.x * w110; acc.y += v110.y * w110; acc.z += v110.z * w110; acc.w += v110.w * w110;
    acc.x += v111.x * w111; acc.y += v111.y * w111; acc.z += v111.z * w111; acc.w += v111.w * w111;

    acc.x = fmaxf(acc.x, 0.0f);
    acc.y = fmaxf(acc.y, 0.0f);
    acc.z = fmaxf(acc.z, 0.0f);
    acc.w = fmaxf(acc.w, 0.0f);

    reinterpret_cast<float4*>(out)[i] = acc;
}

extern "C" void kernel_launch(void* const* d_in, const int* in_sizes, int n_in,
                              void* d_out, int out_size, void* d_ws, size_t ws_size,
                              hipStream_t stream) {
    const float* coords = (const float*)d_in[0];   // [N,3] fp32
    const float* field  = (const float*)d_in[1];   // [256,256,256,4] fp32
    float* out          = (float*)d_out;           // [N,4] fp32

    const int n = in_sizes[0] / 3;                 // N points
    const int block = 256;
    const int grid = (n + block - 1) / block;
    relu_field_kernel<<<grid, block, 0, stream>>>(coords, field, out, n);
}